// Round 1
// baseline (472.873 us; speedup 1.0000x reference)
//
#include <hip/hip_runtime.h>
#include <hip/hip_bf16.h>
#include <math.h>

#define S_TOK 8192
#define N_EXP 64
#define K_DIM 2048
#define CAPACITY 256

// ---------------------------------------------------------------------------
// ws layout (element offsets):
//   [0, 524288)          wgT4   float   : wg transposed to [k/4][e][4]
//   [524288, +8192)      idx1   int
//   [532480, +8192)      idx2   int
//   [540672, +8192)      g1     float   (raw gate prob of top-1)
//   [548864, +8192)      g2     float   (raw gate prob of top-2)
//   [557056, +64)        me_sum float   (sum of gates per expert, atomics)
// ---------------------------------------------------------------------------

__global__ __launch_bounds__(1024) void k_transpose(const float* __restrict__ wg,
                                                    float* __restrict__ wgT4) {
    int idx = blockIdx.x * 1024 + threadIdx.x;      // 131072 elements
    int e = idx >> 11;                              // 0..63
    int k = idx & 2047;                             // 0..2047
    float v = wg[idx];                              // wg[e][k], coalesced read
    wgT4[((k >> 2) << 8) + (e << 2) + (k & 3)] = v; // [k/4][e][4]
}

// 256 blocks x 256 threads. Wave w handles rows blk*32 + w*8 .. +7, lane = expert.
__global__ __launch_bounds__(256) void k_gate(const float* __restrict__ x,
                                              const float* __restrict__ wgT4,
                                              int* __restrict__ idx1,
                                              int* __restrict__ idx2,
                                              float* __restrict__ g1o,
                                              float* __restrict__ g2o,
                                              float* __restrict__ me_sum) {
    __shared__ float wgs[16384];   // 64 KB: one 256-k chunk of wgT4
    __shared__ float me_loc[64];
    const int t = threadIdx.x;
    const int lane = t & 63;
    const int wave = t >> 6;
    if (t < 64) me_loc[t] = 0.0f;
    const int row0 = blockIdx.x * 32 + wave * 8;

    float4 acc[8];
#pragma unroll
    for (int r = 0; r < 8; ++r) acc[r] = make_float4(0.f, 0.f, 0.f, 0.f);

    for (int chunk = 0; chunk < 8; ++chunk) {
        __syncthreads();  // protect previous chunk's LDS reads
        const float4* src = (const float4*)(wgT4 + chunk * 16384);
        float4* dst = (float4*)wgs;
#pragma unroll
        for (int p = 0; p < 16; ++p) dst[p * 256 + t] = src[p * 256 + t];
        __syncthreads();

        const float* xb = x + (size_t)row0 * K_DIM + chunk * 256;
#pragma unroll 2
        for (int k4 = 0; k4 < 64; ++k4) {
            float4 wv = *(const float4*)&wgs[(k4 << 8) + (lane << 2)];
#pragma unroll
            for (int r = 0; r < 8; ++r) {
                float4 xv = *(const float4*)&xb[r * K_DIM + (k4 << 2)];
                acc[r].x = fmaf(xv.x, wv.x, acc[r].x);
                acc[r].y = fmaf(xv.y, wv.y, acc[r].y);
                acc[r].z = fmaf(xv.z, wv.z, acc[r].z);
                acc[r].w = fmaf(xv.w, wv.w, acc[r].w);
            }
        }
    }

    // epilogue: per row, wave-wide softmax + top-2 (lane e holds logit[row][e])
#pragma unroll
    for (int r = 0; r < 8; ++r) {
        float logit = (acc[r].x + acc[r].y) + (acc[r].z + acc[r].w);

        float m1 = logit; int i1 = lane;
#pragma unroll
        for (int off = 32; off > 0; off >>= 1) {
            float om = __shfl_xor(m1, off);
            int oi = __shfl_xor(i1, off);
            if (om > m1 || (om == m1 && oi < i1)) { m1 = om; i1 = oi; }
        }
        float v2 = (lane == i1) ? -INFINITY : logit;
        float m2 = v2; int i2 = lane;
#pragma unroll
        for (int off = 32; off > 0; off >>= 1) {
            float om = __shfl_xor(m2, off);
            int oi = __shfl_xor(i2, off);
            if (om > m2 || (om == m2 && oi < i2)) { m2 = om; i2 = oi; }
        }
        float ex = expf(logit - m1);
        float ssum = ex;
#pragma unroll
        for (int off = 32; off > 0; off >>= 1) ssum += __shfl_xor(ssum, off);

        atomicAdd(&me_loc[lane], ex / ssum);   // gates[row][lane] accumulation

        if (lane == 0) {
            int row = row0 + r;
            idx1[row] = i1;
            idx2[row] = i2;
            g1o[row] = 1.0f / ssum;            // exp(m1-m1)/sum
            g2o[row] = expf(m2 - m1) / ssum;
        }
    }
    __syncthreads();
    if (t < 64) atomicAdd(&me_sum[t], me_loc[t]);
}

// Single block, 1024 threads: prefix counts -> ranks -> scatter + l_aux.
__global__ __launch_bounds__(1024) void k_scan(const int* __restrict__ idx1,
                                               const int* __restrict__ idx2,
                                               const float* __restrict__ g1,
                                               const float* __restrict__ g2,
                                               const float* __restrict__ me_sum,
                                               float* __restrict__ out) {
    __shared__ unsigned char e1b[S_TOK];
    __shared__ unsigned char e2b[S_TOK];
    __shared__ unsigned short l1s[S_TOK];
    __shared__ unsigned short l2s[S_TOK];
    __shared__ int cnt1[16][64];
    __shared__ int cnt2[16][64];
    __shared__ int tot1[64];

    const int t = threadIdx.x;
    for (int i = t; i < S_TOK; i += 1024) {
        e1b[i] = (unsigned char)idx1[i];
        e2b[i] = (unsigned char)idx2[i];
    }
    __syncthreads();

    const int e = t & 63;
    const int ch = t >> 6;           // wave index == chunk -> broadcast LDS reads
    {
        int c1 = 0, c2 = 0;
        const int base = ch * 512;
        for (int i = 0; i < 512; ++i) {
            c1 += (e1b[base + i] == e);
            c2 += (e2b[base + i] == e);
        }
        cnt1[ch][e] = c1;
        cnt2[ch][e] = c2;
    }
    __syncthreads();

    if (t < 64) {
        int b1 = 0, b2 = 0;
        for (int c = 0; c < 16; ++c) {
            int v1 = cnt1[c][t]; cnt1[c][t] = b1; b1 += v1;
            int v2 = cnt2[c][t]; cnt2[c][t] = b2; b2 += v2;
        }
        tot1[t] = b1;                // total count1 per expert (pre-drop)
    }
    __syncthreads();

    {
        int run1 = cnt1[ch][e];
        int run2 = cnt2[ch][e] + tot1[e];   // locations2 includes count1 offset
        const int base = ch * 512;
        for (int i = 0; i < 512; ++i) {
            if (e1b[base + i] == e) l1s[base + i] = (unsigned short)(run1++);
            if (e2b[base + i] == e) l2s[base + i] = (unsigned short)(run2++);
        }
    }
    __syncthreads();

    float* comb = out + 1;
    float* disp = out + 1 + (size_t)S_TOK * N_EXP * CAPACITY;
    for (int s = t; s < S_TOK; s += 1024) {
        int i1 = e1b[s], i2 = e2b[s];
        int l1 = l1s[s], l2 = l2s[s];
        float a = (l1 < CAPACITY) ? g1[s] : 0.0f;
        float b = (l2 < CAPACITY) ? g2[s] : 0.0f;
        float denom = fmaxf(a + b, 1.1920929e-07f);
        if (l1 < CAPACITY) {
            size_t off = ((size_t)s * N_EXP + i1) * CAPACITY + l1;
            comb[off] = a / denom;
            disp[off] = 1.0f;
        }
        if (l2 < CAPACITY) {
            size_t off = ((size_t)s * N_EXP + i2) * CAPACITY + l2;
            comb[off] = b / denom;
            disp[off] = 1.0f;
        }
    }

    if (t < 64) {
        float me = me_sum[t] * (1.0f / S_TOK);
        float ce = (float)tot1[t] * (1.0f / S_TOK);
        float p = me * ce;
#pragma unroll
        for (int off = 32; off > 0; off >>= 1) p += __shfl_xor(p, off);
        if (t == 0) out[0] = p * 64.0f;   // mean(me*ce) * E*E = (sum/64)*4096
    }
}

extern "C" void kernel_launch(void* const* d_in, const int* in_sizes, int n_in,
                              void* d_out, int out_size, void* d_ws, size_t ws_size,
                              hipStream_t stream) {
    (void)in_sizes; (void)n_in; (void)ws_size;
    const float* x  = (const float*)d_in[0];
    const float* wg = (const float*)d_in[1];
    float* out = (float*)d_out;

    float* wgT4   = (float*)d_ws;
    int*   idx1   = (int*)((char*)d_ws + (size_t)524288 * 4);
    int*   idx2   = idx1 + 8192;
    float* g1     = (float*)(idx2 + 8192);
    float* g2     = g1 + 8192;
    float* me_sum = g2 + 8192;

    hipMemsetAsync(d_out, 0, (size_t)out_size * sizeof(float), stream);
    hipMemsetAsync(me_sum, 0, 64 * sizeof(float), stream);
    k_transpose<<<128, 1024, 0, stream>>>(wg, wgT4);
    k_gate<<<256, 256, 0, stream>>>(x, wgT4, idx1, idx2, g1, g2, me_sum);
    k_scan<<<1, 1024, 0, stream>>>(idx1, idx2, g1, g2, me_sum, out);
}

// Round 2
// 278.771 us; speedup vs baseline: 1.6963x; 1.6963x over previous
//
#include <hip/hip_runtime.h>
#include <hip/hip_bf16.h>
#include <math.h>

#define S_TOK 8192
#define N_EXP 64
#define K_DIM 2048
#define CAPACITY 256
#define OUT_F4 67108864ull            // (out_size-1)/4 float4s covering [0, 268435456)
#define LAST_ELEM 268435456ull        // final odd float (disp[8191][63][255])
#define ROWS_PB 16
#define KC 128

// ws layout (float elements):
//   [0, 524288)        wgT4  : wg transposed to [k/4][e][4]
//   [524288, +8192)    idx1 (int)
//   [532480, +8192)    idx2 (int)
//   [540672, +8192)    g1
//   [548864, +8192)    g2
//   [557056, +64)      me_sum

__global__ __launch_bounds__(1024) void k_transpose(const float* __restrict__ wg,
                                                    float* __restrict__ wgT4,
                                                    float* __restrict__ me_sum) {
    int idx = blockIdx.x * 1024 + threadIdx.x;      // 131072 elements
    int e = idx >> 11;
    int k = idx & 2047;
    float v = wg[idx];
    wgT4[((k >> 2) << 8) + (e << 2) + (k & 3)] = v;
    if (blockIdx.x == 0 && threadIdx.x < 64) me_sum[threadIdx.x] = 0.0f;
}

// 512 blocks x 256 threads. Block handles 16 rows; wave w: rows w*4..w*4+3, lane = expert.
// Also zero-fills output floats [b*524288, (b+1)*524288) interleaved with compute.
__global__ __launch_bounds__(256) void k_gate_fill(const float* __restrict__ x,
                                                   const float* __restrict__ wgT4,
                                                   float* __restrict__ out,
                                                   int* __restrict__ idx1,
                                                   int* __restrict__ idx2,
                                                   float* __restrict__ g1o,
                                                   float* __restrict__ g2o,
                                                   float* __restrict__ me_sum) {
    __shared__ float wgs[KC * 64];      // 32 KB: [k4local][e][4]
    __shared__ float xs[ROWS_PB * KC];  // 8 KB:  [row][k]
    __shared__ float me_loc[64];
    const int t = threadIdx.x;
    const int lane = t & 63;
    const int w = t >> 6;
    const int b = blockIdx.x;
    const int row0 = b * ROWS_PB;
    if (t < 64) me_loc[t] = 0.0f;

    float4 acc[4];
#pragma unroll
    for (int r = 0; r < 4; ++r) acc[r] = make_float4(0.f, 0.f, 0.f, 0.f);

    float4* outf4 = (float4*)out;
    const float4 z4 = make_float4(0.f, 0.f, 0.f, 0.f);

    for (int c = 0; c < 16; ++c) {
        __syncthreads();  // previous chunk's LDS reads done
        // stage wg chunk (2048 f4, coalesced)
        const float4* wsrc = (const float4*)(wgT4 + c * (KC * 64));
        float4* wdst = (float4*)wgs;
#pragma unroll
        for (int i = 0; i < 8; ++i) wdst[i * 256 + t] = wsrc[i * 256 + t];
        // stage x chunk (512 f4)
        {
            float4* xdst = (float4*)xs;
            int f4 = t;
            int r = f4 >> 5, p = f4 & 31;
            xdst[f4] = *(const float4*)&x[(size_t)(row0 + r) * K_DIM + c * KC + p * 4];
            f4 = t + 256;
            r = f4 >> 5; p = f4 & 31;
            xdst[f4] = *(const float4*)&x[(size_t)(row0 + r) * K_DIM + c * KC + p * 4];
        }
        // zero-fill 32 f4 of this block's output slice
        {
            size_t base = (size_t)b * 131072 + (size_t)c * 8192 + t;
#pragma unroll
            for (int i = 0; i < 32; ++i) outf4[base + (size_t)i * 256] = z4;
        }
        __syncthreads();
        // compute: 32 k4-steps, 4 rows
#pragma unroll 4
        for (int k4 = 0; k4 < 32; ++k4) {
            float4 wv = *(const float4*)&wgs[k4 * 256 + lane * 4];
#pragma unroll
            for (int r = 0; r < 4; ++r) {
                float4 xv = *(const float4*)&xs[(w * 4 + r) * KC + k4 * 4];
                acc[r].x = fmaf(xv.x, wv.x, acc[r].x);
                acc[r].y = fmaf(xv.y, wv.y, acc[r].y);
                acc[r].z = fmaf(xv.z, wv.z, acc[r].z);
                acc[r].w = fmaf(xv.w, wv.w, acc[r].w);
            }
        }
    }

    // epilogue: per wave, 4 rows of softmax + top-2 (lane e holds logit[row][e])
#pragma unroll
    for (int r = 0; r < 4; ++r) {
        float logit = (acc[r].x + acc[r].y) + (acc[r].z + acc[r].w);

        float m1 = logit; int i1 = lane;
#pragma unroll
        for (int off = 32; off > 0; off >>= 1) {
            float om = __shfl_xor(m1, off);
            int oi = __shfl_xor(i1, off);
            if (om > m1 || (om == m1 && oi < i1)) { m1 = om; i1 = oi; }
        }
        float v2 = (lane == i1) ? -INFINITY : logit;
        float m2 = v2; int i2 = lane;
#pragma unroll
        for (int off = 32; off > 0; off >>= 1) {
            float om = __shfl_xor(m2, off);
            int oi = __shfl_xor(i2, off);
            if (om > m2 || (om == m2 && oi < i2)) { m2 = om; i2 = oi; }
        }
        float ex = expf(logit - m1);
        float ssum = ex;
#pragma unroll
        for (int off = 32; off > 0; off >>= 1) ssum += __shfl_xor(ssum, off);

        atomicAdd(&me_loc[lane], ex / ssum);

        if (lane == 0) {
            int row = row0 + w * 4 + r;
            idx1[row] = i1;
            idx2[row] = i2;
            g1o[row] = 1.0f / ssum;
            g2o[row] = expf(m2 - m1) / ssum;
        }
    }
    __syncthreads();
    if (t < 64) atomicAdd(&me_sum[t], me_loc[t]);
}

// Single block, 1024 threads: ballot-based ranks -> finalize -> scatter + l_aux.
__global__ __launch_bounds__(1024) void k_scan(const int* __restrict__ idx1,
                                               const int* __restrict__ idx2,
                                               const float* __restrict__ g1,
                                               const float* __restrict__ g2,
                                               const float* __restrict__ me_sum,
                                               float* __restrict__ out) {
    __shared__ int cnt[2][128][64];   // per-group per-expert counts -> exclusive prefix
    __shared__ int tot1[64];

    const int t = threadIdx.x;
    const int lane = t & 63;
    const int w = t >> 6;

    // zero histograms; also pre-zero the final odd output element (ordered via barrier)
    int* cz = &cnt[0][0][0];
    for (int i = t; i < 2 * 128 * 64; i += 1024) cz[i] = 0;
    if (t == 0) out[LAST_ELEM] = 0.0f;
    __syncthreads();

    int e1[8], e2[8], r1[8], r2[8];
#pragma unroll
    for (int j = 0; j < 8; ++j) {
        int g = w * 8 + j;            // group of 64 tokens
        int tok = g * 64 + lane;
        int a = idx1[tok];
        int bq = idx2[tok];
        e1[j] = a; e2[j] = bq;
        unsigned long long s1 = ~0ull, s2 = ~0ull;
#pragma unroll
        for (int bit = 0; bit < 6; ++bit) {
            unsigned long long ba = __ballot((a >> bit) & 1);
            unsigned long long bb = __ballot((bq >> bit) & 1);
            s1 &= ((a >> bit) & 1) ? ba : ~ba;
            s2 &= ((bq >> bit) & 1) ? bb : ~bb;
        }
        unsigned long long below = (lane == 0) ? 0ull : (~0ull >> (64 - lane));
        r1[j] = __popcll(s1 & below);
        r2[j] = __popcll(s2 & below);
        if (r1[j] == 0) cnt[0][g][a] = __popcll(s1);
        if (r2[j] == 0) cnt[1][g][bq] = __popcll(s2);
    }
    __syncthreads();

    // exclusive prefix over groups, per expert (wave 0: top-1 table, wave 1: top-2 table)
    if (t < 128) {
        int which = t >> 6, e = t & 63;
        int run = 0;
        for (int g = 0; g < 128; ++g) {
            int v = cnt[which][g][e];
            cnt[which][g][e] = run;
            run += v;
        }
        if (which == 0) tot1[e] = run;
    }
    __syncthreads();

    float* comb = out + 1;
    float* disp = out + 1 + (size_t)S_TOK * N_EXP * CAPACITY;
#pragma unroll
    for (int j = 0; j < 8; ++j) {
        int g = w * 8 + j;
        int tok = g * 64 + lane;
        int l1 = cnt[0][g][e1[j]] + r1[j];
        int l2 = cnt[1][g][e2[j]] + r2[j] + tot1[e2[j]];
        float a = (l1 < CAPACITY) ? g1[tok] : 0.0f;
        float b = (l2 < CAPACITY) ? g2[tok] : 0.0f;
        float denom = fmaxf(a + b, 1.1920929e-07f);
        if (l1 < CAPACITY) {
            size_t off = ((size_t)tok * N_EXP + e1[j]) * CAPACITY + l1;
            comb[off] = a / denom;
            disp[off] = 1.0f;
        }
        if (l2 < CAPACITY) {
            size_t off = ((size_t)tok * N_EXP + e2[j]) * CAPACITY + l2;
            comb[off] = b / denom;
            disp[off] = 1.0f;
        }
    }

    if (t < 64) {
        float me = me_sum[t] * (1.0f / S_TOK);
        float ce = (float)tot1[t] * (1.0f / S_TOK);
        float p = me * ce;
#pragma unroll
        for (int off = 32; off > 0; off >>= 1) p += __shfl_xor(p, off);
        if (t == 0) out[0] = p * 64.0f;   // mean(me*ce)*E*E
    }
}

extern "C" void kernel_launch(void* const* d_in, const int* in_sizes, int n_in,
                              void* d_out, int out_size, void* d_ws, size_t ws_size,
                              hipStream_t stream) {
    (void)in_sizes; (void)n_in; (void)ws_size; (void)out_size;
    const float* x  = (const float*)d_in[0];
    const float* wg = (const float*)d_in[1];
    float* out = (float*)d_out;

    float* wgT4   = (float*)d_ws;
    int*   idx1   = (int*)((char*)d_ws + (size_t)524288 * 4);
    int*   idx2   = idx1 + 8192;
    float* g1     = (float*)(idx2 + 8192);
    float* g2     = g1 + 8192;
    float* me_sum = g2 + 8192;

    k_transpose<<<128, 1024, 0, stream>>>(wg, wgT4, me_sum);
    k_gate_fill<<<512, 256, 0, stream>>>(x, wgT4, out, idx1, idx2, g1, g2, me_sum);
    k_scan<<<1, 1024, 0, stream>>>(idx1, idx2, g1, g2, me_sum, out);
}

// Round 4
// 176.410 us; speedup vs baseline: 2.6805x; 1.5802x over previous
//
#include <hip/hip_runtime.h>
#include <hip/hip_bf16.h>
#include <math.h>

#define S_TOK 8192
#define N_EXP 64
#define K_DIM 2048
#define CAPACITY 256
#define LAST_ELEM 268435456ull        // final odd float (disp[8191][63][255])
#define ROWS_PB 16
#define KC 128
#define N_COMPUTE 512
#define N_BLOCKS 2048
#define FILL_CHUNK_F4 8192            // 128 KB per steal
#define N_FILL_CHUNKS 8192            // 8192 * 8192 f4 = 268435456 floats

typedef float vfloat4 __attribute__((ext_vector_type(4)));

// ws layout (float elements):
//   [0, 524288)        wgT4  : wg transposed to [k/4][e][4]
//   [524288, +8192)    idx1 (int)
//   [532480, +8192)    idx2 (int)
//   [540672, +8192)    g1
//   [548864, +8192)    g2
//   [557056, +64)      me_sum
//   [557120, +1)       fill_ctr (int)

__global__ __launch_bounds__(1024) void k_transpose(const float* __restrict__ wg,
                                                    float* __restrict__ wgT4,
                                                    float* __restrict__ me_sum,
                                                    int* __restrict__ fill_ctr) {
    int idx = blockIdx.x * 1024 + threadIdx.x;      // 131072 elements
    int e = idx >> 11;
    int k = idx & 2047;
    float v = wg[idx];
    wgT4[((k >> 2) << 8) + (e << 2) + (k & 3)] = v;
    if (blockIdx.x == 0 && threadIdx.x < 64) me_sum[threadIdx.x] = 0.0f;
    if (blockIdx.x == 0 && threadIdx.x == 64) *fill_ctr = 0;
}

// 2048 blocks x 256 threads.
//  blocks [0,512): gate GEMM for 16 rows each (then join fill pool)
//  blocks [512,2048): barrier-free work-stealing zero-fill of out[0..268435456)
__global__ __launch_bounds__(256) void k_gate_fill(const float* __restrict__ x,
                                                   const float* __restrict__ wgT4,
                                                   float* __restrict__ out,
                                                   int* __restrict__ idx1,
                                                   int* __restrict__ idx2,
                                                   float* __restrict__ g1o,
                                                   float* __restrict__ g2o,
                                                   float* __restrict__ me_sum,
                                                   int* __restrict__ fill_ctr) {
    __shared__ float wgs[KC * 64];      // 32 KB: [k4local][e][4]
    __shared__ float xs[ROWS_PB * KC];  // 8 KB:  [row][k]
    __shared__ float me_loc[64];
    const int t = threadIdx.x;
    const int b = blockIdx.x;
    vfloat4* outv4 = (vfloat4*)out;
    const vfloat4 z4 = (vfloat4){0.f, 0.f, 0.f, 0.f};

    if (b < N_COMPUTE) {
        const int lane = t & 63;
        const int w = t >> 6;
        const int row0 = b * ROWS_PB;
        if (t < 64) me_loc[t] = 0.0f;

        float4 acc[4];
#pragma unroll
        for (int r = 0; r < 4; ++r) acc[r] = make_float4(0.f, 0.f, 0.f, 0.f);

        for (int c = 0; c < 16; ++c) {
            __syncthreads();  // previous chunk's LDS reads done
            const float4* wsrc = (const float4*)(wgT4 + c * (KC * 64));
            float4* wdst = (float4*)wgs;
#pragma unroll
            for (int i = 0; i < 8; ++i) wdst[i * 256 + t] = wsrc[i * 256 + t];
            {
                float4* xdst = (float4*)xs;
                int f4 = t;
                int r = f4 >> 5, p = f4 & 31;
                xdst[f4] = *(const float4*)&x[(size_t)(row0 + r) * K_DIM + c * KC + p * 4];
                f4 = t + 256;
                r = f4 >> 5; p = f4 & 31;
                xdst[f4] = *(const float4*)&x[(size_t)(row0 + r) * K_DIM + c * KC + p * 4];
            }
            __syncthreads();
#pragma unroll 4
            for (int k4 = 0; k4 < 32; ++k4) {
                float4 wv = *(const float4*)&wgs[k4 * 256 + lane * 4];
#pragma unroll
                for (int r = 0; r < 4; ++r) {
                    float4 xv = *(const float4*)&xs[(w * 4 + r) * KC + k4 * 4];
                    acc[r].x = fmaf(xv.x, wv.x, acc[r].x);
                    acc[r].y = fmaf(xv.y, wv.y, acc[r].y);
                    acc[r].z = fmaf(xv.z, wv.z, acc[r].z);
                    acc[r].w = fmaf(xv.w, wv.w, acc[r].w);
                }
            }
        }

        // epilogue: per wave, 4 rows of softmax + top-2 (lane e holds logit[row][e])
#pragma unroll
        for (int r = 0; r < 4; ++r) {
            float logit = (acc[r].x + acc[r].y) + (acc[r].z + acc[r].w);

            float m1 = logit; int i1 = lane;
#pragma unroll
            for (int off = 32; off > 0; off >>= 1) {
                float om = __shfl_xor(m1, off);
                int oi = __shfl_xor(i1, off);
                if (om > m1 || (om == m1 && oi < i1)) { m1 = om; i1 = oi; }
            }
            float v2 = (lane == i1) ? -INFINITY : logit;
            float m2 = v2; int i2 = lane;
#pragma unroll
            for (int off = 32; off > 0; off >>= 1) {
                float om = __shfl_xor(m2, off);
                int oi = __shfl_xor(i2, off);
                if (om > m2 || (om == m2 && oi < i2)) { m2 = om; i2 = oi; }
            }
            float ex = expf(logit - m1);
            float ssum = ex;
#pragma unroll
            for (int off = 32; off > 0; off >>= 1) ssum += __shfl_xor(ssum, off);

            atomicAdd(&me_loc[lane], ex / ssum);

            if (lane == 0) {
                int row = row0 + w * 4 + r;
                idx1[row] = i1;
                idx2[row] = i2;
                g1o[row] = 1.0f / ssum;
                g2o[row] = expf(m2 - m1) / ssum;
            }
        }
        __syncthreads();
        if (t < 64) atomicAdd(&me_sum[t], me_loc[t]);
        // fall through: join the fill pool
    }

    // barrier-free work-stealing zero-fill
    for (;;) {
        int c = atomicAdd(fill_ctr, 1);
        if (c >= N_FILL_CHUNKS) break;
        size_t base = (size_t)c * FILL_CHUNK_F4 + t;
#pragma unroll
        for (int i = 0; i < 32; ++i)
            __builtin_nontemporal_store(z4, &outv4[base + (size_t)i * 256]);
    }
}

// Single block, 1024 threads: ballot-based ranks -> finalize -> scatter + l_aux.
__global__ __launch_bounds__(1024) void k_scan(const int* __restrict__ idx1,
                                               const int* __restrict__ idx2,
                                               const float* __restrict__ g1,
                                               const float* __restrict__ g2,
                                               const float* __restrict__ me_sum,
                                               float* __restrict__ out) {
    __shared__ int cnt[2][128][64];   // per-group per-expert counts -> exclusive prefix
    __shared__ int tot1[64];

    const int t = threadIdx.x;
    const int lane = t & 63;
    const int w = t >> 6;

    int* cz = &cnt[0][0][0];
    for (int i = t; i < 2 * 128 * 64; i += 1024) cz[i] = 0;
    if (t == 0) out[LAST_ELEM] = 0.0f;
    __syncthreads();

    int e1[8], e2[8], r1[8], r2[8];
#pragma unroll
    for (int j = 0; j < 8; ++j) {
        int g = w * 8 + j;            // group of 64 tokens
        int tok = g * 64 + lane;
        int a = idx1[tok];
        int bq = idx2[tok];
        e1[j] = a; e2[j] = bq;
        unsigned long long s1 = ~0ull, s2 = ~0ull;
#pragma unroll
        for (int bit = 0; bit < 6; ++bit) {
            unsigned long long ba = __ballot((a >> bit) & 1);
            unsigned long long bb = __ballot((bq >> bit) & 1);
            s1 &= ((a >> bit) & 1) ? ba : ~ba;
            s2 &= ((bq >> bit) & 1) ? bb : ~bb;
        }
        unsigned long long below = (lane == 0) ? 0ull : (~0ull >> (64 - lane));
        r1[j] = __popcll(s1 & below);
        r2[j] = __popcll(s2 & below);
        if (r1[j] == 0) cnt[0][g][a] = __popcll(s1);
        if (r2[j] == 0) cnt[1][g][bq] = __popcll(s2);
    }
    __syncthreads();

    if (t < 128) {
        int which = t >> 6, e = t & 63;
        int run = 0;
        for (int g = 0; g < 128; ++g) {
            int v = cnt[which][g][e];
            cnt[which][g][e] = run;
            run += v;
        }
        if (which == 0) tot1[e] = run;
    }
    __syncthreads();

    float* comb = out + 1;
    float* disp = out + 1 + (size_t)S_TOK * N_EXP * CAPACITY;
#pragma unroll
    for (int j = 0; j < 8; ++j) {
        int g = w * 8 + j;
        int tok = g * 64 + lane;
        int l1 = cnt[0][g][e1[j]] + r1[j];
        int l2 = cnt[1][g][e2[j]] + r2[j] + tot1[e2[j]];
        float a = (l1 < CAPACITY) ? g1[tok] : 0.0f;
        float b = (l2 < CAPACITY) ? g2[tok] : 0.0f;
        float denom = fmaxf(a + b, 1.1920929e-07f);
        if (l1 < CAPACITY) {
            size_t off = ((size_t)tok * N_EXP + e1[j]) * CAPACITY + l1;
            comb[off] = a / denom;
            disp[off] = 1.0f;
        }
        if (l2 < CAPACITY) {
            size_t off = ((size_t)tok * N_EXP + e2[j]) * CAPACITY + l2;
            comb[off] = b / denom;
            disp[off] = 1.0f;
        }
    }

    if (t < 64) {
        float me = me_sum[t] * (1.0f / S_TOK);
        float ce = (float)tot1[t] * (1.0f / S_TOK);
        float p = me * ce;
#pragma unroll
        for (int off = 32; off > 0; off >>= 1) p += __shfl_xor(p, off);
        if (t == 0) out[0] = p * 64.0f;   // mean(me*ce)*E*E
    }
}

extern "C" void kernel_launch(void* const* d_in, const int* in_sizes, int n_in,
                              void* d_out, int out_size, void* d_ws, size_t ws_size,
                              hipStream_t stream) {
    (void)in_sizes; (void)n_in; (void)ws_size; (void)out_size;
    const float* x  = (const float*)d_in[0];
    const float* wg = (const float*)d_in[1];
    float* out = (float*)d_out;

    float* wgT4     = (float*)d_ws;
    int*   idx1     = (int*)((char*)d_ws + (size_t)524288 * 4);
    int*   idx2     = idx1 + 8192;
    float* g1       = (float*)(idx2 + 8192);
    float* g2       = g1 + 8192;
    float* me_sum   = g2 + 8192;
    int*   fill_ctr = (int*)(me_sum + 64);

    k_transpose<<<128, 1024, 0, stream>>>(wg, wgT4, me_sum, fill_ctr);
    k_gate_fill<<<N_BLOCKS, 256, 0, stream>>>(x, wgT4, out, idx1, idx2, g1, g2,
                                              me_sum, fill_ctr);
    k_scan<<<1, 1024, 0, stream>>>(idx1, idx2, g1, g2, me_sum, out);
}